// Round 14
// baseline (124.486 us; speedup 1.0000x reference)
//
#include <hip/hip_runtime.h>
#include <hip/hip_bf16.h>
#include <math.h>

// Problem constants
#define B_    16
#define D_    256
#define T_    2048
#define K_    1024
#define BT_   (B_ * T_)            // 32768 rows
#define BDT_  (B_ * D_ * T_)       // 8388608 elements
#define MUSIC_W 0.1f
#define EPS_COS 1e-8f
#define MARGIN_TAU 2e-4f           // > np ulp-grid (1.26e-4) + fp16 MFMA err + key quant (~4e-6)

typedef _Float16 half8v __attribute__((ext_vector_type(8)));
typedef float f32x4 __attribute__((ext_vector_type(4)));

// ---------------------------------------------------------------------------
// numpy pairwise sum-of-squares (exact replication for n=128 / n=256).
// ---------------------------------------------------------------------------
__device__ __forceinline__ float pw128_sq(const float* a, int stride) {
    float r[8];
    #pragma unroll
    for (int j = 0; j < 8; ++j) { float v = a[j * stride]; r[j] = __fmul_rn(v, v); }
    for (int i = 8; i < 128; i += 8) {
        #pragma unroll
        for (int j = 0; j < 8; ++j) {
            float v = a[(i + j) * stride];
            r[j] = __fadd_rn(r[j], __fmul_rn(v, v));
        }
    }
    return __fadd_rn(__fadd_rn(__fadd_rn(r[0], r[1]), __fadd_rn(r[2], r[3])),
                     __fadd_rn(__fadd_rn(r[4], r[5]), __fadd_rn(r[6], r[7])));
}
__device__ __forceinline__ float pw256_sq(const float* a, int stride) {
    return __fadd_rn(pw128_sq(a, stride), pw128_sq(a + 128 * stride, stride));
}

// np score for one (row, code): M = f32(round(f64 dot)); s = fl(fl(xx-2M)+cc).
__device__ __forceinline__ float np_score(const float* __restrict__ xr,
                                          const float* __restrict__ cp,
                                          float xxv, float c2k) {
    double a0 = 0.0, a1 = 0.0, a2 = 0.0, a3 = 0.0;
    for (int d = 0; d < 256; d += 4) {
        float4 cv = *(const float4*)(cp + d);
        a0 = fma((double)xr[d + 0], (double)cv.x, a0);
        a1 = fma((double)xr[d + 1], (double)cv.y, a1);
        a2 = fma((double)xr[d + 2], (double)cv.z, a2);
        a3 = fma((double)xr[d + 3], (double)cv.w, a3);
    }
    float M = (float)((a0 + a1) + (a2 + a3));
    return __fadd_rn(__fsub_rn(xxv, __fmul_rn(2.0f, M)), c2k);
}

// order-preserving key transforms (ascending)
__device__ __forceinline__ unsigned key_fwd(float s) {
    unsigned u = __float_as_uint(s);
    return u ^ ((unsigned)((int)u >> 31) | 0x80000000u);
}
__device__ __forceinline__ float key_inv(unsigned key) {
    unsigned u = (key & 0x80000000u) ? (key ^ 0x80000000u) : ~key;
    return __uint_as_float(u);
}

// ---------------------------------------------------------------------------
// Kernel 1: prep — cph packed fp16 codebook [d/8][k][8], wh fp16 W-panel,
// c2[k] numpy-pairwise, zero counts / sums.
// ---------------------------------------------------------------------------
__global__ __launch_bounds__(256) void prep_kernel(const float* __restrict__ cb,
                                                   const float* __restrict__ wp,
                                                   _Float16* __restrict__ cph,
                                                   _Float16* __restrict__ wh,
                                                   float* __restrict__ c2,
                                                   float* __restrict__ counts,
                                                   double* __restrict__ sums) {
    __shared__ float rr[16];
    int k = blockIdx.x;        // 0..1023
    int d = threadIdx.x;       // 0..255
    const float* a = cb + (size_t)k * D_;
    float v = a[d];
    cph[((d >> 3) * K_ + k) * 8 + (d & 7)] = (_Float16)v;
    if (k < 16) {
        _Float16 hv = (k < 3) ? (_Float16)wp[k * D_ + d] : (_Float16)0.0f;
        wh[((d >> 3) * 16 + k) * 8 + (d & 7)] = hv;
    }
    if (d < 8) {
        float acc = __fmul_rn(a[d], a[d]);
        for (int i = 8; i < 128; i += 8) acc = __fadd_rn(acc, __fmul_rn(a[i + d], a[i + d]));
        rr[d] = acc;
        float acc2 = __fmul_rn(a[128 + d], a[128 + d]);
        for (int i = 8; i < 128; i += 8) acc2 = __fadd_rn(acc2, __fmul_rn(a[128 + i + d], a[128 + i + d]));
        rr[8 + d] = acc2;
    }
    __syncthreads();
    if (d == 0) {
        float h1 = __fadd_rn(__fadd_rn(__fadd_rn(rr[0], rr[1]), __fadd_rn(rr[2], rr[3])),
                             __fadd_rn(__fadd_rn(rr[4], rr[5]), __fadd_rn(rr[6], rr[7])));
        float h2 = __fadd_rn(__fadd_rn(__fadd_rn(rr[8], rr[9]), __fadd_rn(rr[10], rr[11])),
                             __fadd_rn(__fadd_rn(rr[12], rr[13]), __fadd_rn(rr[14], rr[15])));
        c2[k] = __fadd_rn(h1, h2);
        counts[k] = 0.0f;
    }
    if (k == 0 && d < 2) sums[d] = 0.0;
}

// ---------------------------------------------------------------------------
// Kernel 2: mega-kernel — 64 rows/block, 512 threads (8 waves), 512 blocks.
// launch_bounds(512, 2): VGPR cap 256, compiler lands ~104 -> 2 blocks/CU
// co-resident = 16 waves/CU (the R12 geometry WITHOUT the 64-VGPR cap).
// fp16 MFMA argmin (packed-key top-2, wave w covers 128 codes),
// candidate-only np fallback, fused music (waves 0-3), fused histogram,
// fused quantized output + commitment sum.
// ---------------------------------------------------------------------------
#define HSTR 264   // fp16 tile row stride (halfs)

__global__ __launch_bounds__(512, 2) void argmin_kernel(const float* __restrict__ x,
                                                        const float* __restrict__ mc,
                                                        const float* __restrict__ bp,
                                                        const _Float16* __restrict__ cph,
                                                        const _Float16* __restrict__ wh,
                                                        const float* __restrict__ cb,
                                                        const float* __restrict__ c2,
                                                        int* __restrict__ codes,
                                                        float* __restrict__ codes_f,
                                                        float* __restrict__ sim,
                                                        float* __restrict__ counts,
                                                        float* __restrict__ out0,
                                                        double* __restrict__ sums) {
    __shared__ __align__(16) _Float16 xh[64 * HSTR];   // 33792 B
    __shared__ __align__(16) float xrow[256];
    __shared__ unsigned wb1[8][64], wb2[8][64];
    __shared__ float rbest[64];
    __shared__ int   rcode[64];
    __shared__ int   fb_list[64];
    __shared__ int   fb_n;
    __shared__ float fbv_s[8];
    __shared__ int   fbk_s[8];
    __shared__ float bs[3];
    __shared__ float qpart[8];

    int blk = blockIdx.x;            // 0..511
    int row0 = blk * 64;
    int b = row0 >> 11;
    int t0 = row0 & 2047;
    const float* xb = x + (size_t)b * (D_ * T_);

    int tid = threadIdx.x;
    if (tid == 0) fb_n = 0;
    if (tid < 3) bs[tid] = bp[tid];

    // staging: thread (li, dhi) covers row t0+li, dims [dhi*32, dhi*32+32)
    int li = tid & 63;
    int dhi = tid >> 6;              // 0..7
    #pragma unroll
    for (int q = 0; q < 4; ++q) {
        half8v hv;
        #pragma unroll
        for (int j = 0; j < 8; ++j) {
            float v = xb[(size_t)(dhi * 32 + q * 8 + j) * T_ + t0 + li];
            hv[j] = (_Float16)v;
        }
        *(half8v*)&xh[li * HSTR + dhi * 32 + q * 8] = hv;
    }
    __syncthreads();

    int wave = tid >> 6;             // 0..7
    int lane = tid & 63;
    int lmod = lane & 15;
    int lgrp = lane >> 4;            // 0..3

    // resident A fragments for m-tiles 0,1; mt 2,3 re-read from LDS per nt
    half8v afrag[2][8];
    #pragma unroll
    for (int mt = 0; mt < 2; ++mt)
        #pragma unroll
        for (int kb = 0; kb < 8; ++kb)
            afrag[mt][kb] = *(const half8v*)&xh[(mt * 16 + lmod) * HSTR + lgrp * 8 + kb * 32];

    // packed top-2 keys per row slot (16 slots: row = (r>>2)*16 + lgrp*4 + (r&3))
    unsigned b1[16], b2[16];
    #pragma unroll
    for (int r = 0; r < 16; ++r) { b1[r] = 0xFFFFFFFFu; b2[r] = 0xFFFFFFFFu; }

    // main loop: wave w covers codes [w*128, w*128+128) -> 8 n-tiles
    #pragma unroll 1
    for (int nt = 0; nt < 8; ++nt) {
        int n = wave * 128 + nt * 16 + lmod;
        half8v bfr[8];
        #pragma unroll
        for (int kb = 0; kb < 8; ++kb)
            bfr[kb] = *(const half8v*)(cph + ((size_t)((kb << 2) + lgrp) * K_ + n) * 8);
        float c2n = c2[n];
        #pragma unroll
        for (int mt = 0; mt < 2; ++mt) {
            f32x4 acc = {0.f, 0.f, 0.f, 0.f};
            #pragma unroll
            for (int kb = 0; kb < 8; ++kb)
                acc = __builtin_amdgcn_mfma_f32_16x16x32_f16(afrag[mt][kb], bfr[kb], acc, 0, 0, 0);
            #pragma unroll
            for (int i = 0; i < 4; ++i) {
                float s = fmaf(-2.0f, acc[i], c2n);
                unsigned u = (key_fwd(s) & 0xFFFFFC00u) | (unsigned)n;
                int r = mt * 4 + i;
                unsigned mx = b1[r] > u ? b1[r] : u;
                b1[r] = b1[r] < u ? b1[r] : u;
                b2[r] = b2[r] < mx ? b2[r] : mx;
            }
        }
        #pragma unroll
        for (int mt = 2; mt < 4; ++mt) {
            f32x4 acc = {0.f, 0.f, 0.f, 0.f};
            #pragma unroll
            for (int kb = 0; kb < 8; ++kb) {
                half8v av = *(const half8v*)&xh[(mt * 16 + lmod) * HSTR + lgrp * 8 + kb * 32];
                acc = __builtin_amdgcn_mfma_f32_16x16x32_f16(av, bfr[kb], acc, 0, 0, 0);
            }
            #pragma unroll
            for (int i = 0; i < 4; ++i) {
                float s = fmaf(-2.0f, acc[i], c2n);
                unsigned u = (key_fwd(s) & 0xFFFFFC00u) | (unsigned)n;
                int r = mt * 4 + i;
                unsigned mx = b1[r] > u ? b1[r] : u;
                b1[r] = b1[r] < u ? b1[r] : u;
                b2[r] = b2[r] < mx ? b2[r] : mx;
            }
        }
    }

    // cross-lane top-2 merge over the 16 lanes sharing lgrp
    #pragma unroll
    for (int r = 0; r < 16; ++r) {
        unsigned v1 = b1[r], v2 = b2[r];
        #pragma unroll
        for (int off = 1; off < 16; off <<= 1) {
            unsigned o1 = (unsigned)__shfl_xor((int)v1, off, 64);
            unsigned o2 = (unsigned)__shfl_xor((int)v2, off, 64);
            unsigned mx = v1 > o1 ? v1 : o1;
            v1 = v1 < o1 ? v1 : o1;
            unsigned m2 = v2 < o2 ? v2 : o2;
            v2 = m2 < mx ? m2 : mx;
        }
        if (lmod == 0) {
            int row = (r >> 2) * 16 + lgrp * 4 + (r & 3);
            wb1[wave][row] = v1; wb2[wave][row] = v2;
        }
    }
    __syncthreads();

    // cross-wave merge (waves ascend in k); commit wide-margin rows, flag ties
    if (tid < 64) {
        unsigned B1 = wb1[0][tid], B2 = wb2[0][tid];
        #pragma unroll
        for (int w = 1; w < 8; ++w) {
            unsigned o1 = wb1[w][tid], o2 = wb2[w][tid];
            unsigned mx = B1 > o1 ? B1 : o1;
            B1 = B1 < o1 ? B1 : o1;
            unsigned m2 = B2 < o2 ? B2 : o2;
            B2 = m2 < mx ? m2 : mx;
        }
        float f1 = key_inv(B1 & 0xFFFFFC00u);
        float f2 = key_inv(B2 & 0xFFFFFC00u);
        rbest[tid] = f1;
        int row = row0 + tid;
        if (f2 - f1 >= MARGIN_TAU) {
            int bk = (int)(B1 & 1023u);
            rcode[tid] = bk;
            codes[row] = bk;
            codes_f[row] = (float)bk;
            atomicAdd(&counts[bk], 1.0f);
        } else {
            int slot = atomicAdd(&fb_n, 1);
            fb_list[slot] = tid;
        }
    }
    __syncthreads();

    // ---- candidate-only np-replication fallback for near-tie rows
    int nf = fb_n;
    for (int fi = 0; fi < nf; ++fi) {
        int lr = fb_list[fi];
        float rb = rbest[lr];
        if (tid < 256) xrow[tid] = xb[(size_t)tid * T_ + t0 + lr];   // exact f32 row
        __syncthreads();

        int ri = (((lr >> 2) & 3) == lgrp) ? ((lr >> 4) * 4 + (lr & 3)) : -1;
        unsigned k1 = 0xFFFFFFFFu, k2 = 0xFFFFFFFFu;
        #pragma unroll
        for (int r = 0; r < 16; ++r) {
            if (r == ri) { k1 = b1[r]; k2 = b2[r]; }
        }
        float f1s = key_inv(k1 & 0xFFFFFC00u);
        float f2s = key_inv(k2 & 0xFFFFFC00u);
        int f1k = (int)(k1 & 1023u), f2k = (int)(k2 & 1023u);

        float xxv = pw256_sq(xrow, 1);   // np-pairwise |x|^2 (uniform LDS reads)

        float bv = 3.4e38f; int bk = -1;
        if (ri >= 0 && f1s <= rb + MARGIN_TAU) {
            bv = np_score(xrow, cb + (size_t)f1k * D_, xxv, c2[f1k]);
            bk = f1k;
        }
        if (ri >= 0 && f2s <= rb + MARGIN_TAU) {
            float sB = np_score(xrow, cb + (size_t)f2k * D_, xxv, c2[f2k]);
            if (sB < bv || (sB == bv && (unsigned)f2k < (unsigned)bk)) { bv = sB; bk = f2k; }
        }
        #pragma unroll
        for (int off = 1; off < 64; off <<= 1) {
            float ov = __shfl_xor(bv, off, 64);
            int ok = __shfl_xor(bk, off, 64);
            if (ov < bv || (ov == bv && (unsigned)ok < (unsigned)bk)) { bv = ov; bk = ok; }
        }
        if (lane == 0) { fbv_s[wave] = bv; fbk_s[wave] = bk; }
        __syncthreads();
        if (tid == 0) {
            float Bv = fbv_s[0]; int Bk = fbk_s[0];
            #pragma unroll
            for (int w = 1; w < 8; ++w) {
                if (fbv_s[w] < Bv || (fbv_s[w] == Bv && (unsigned)fbk_s[w] < (unsigned)Bk)) {
                    Bv = fbv_s[w]; Bk = fbk_s[w];
                }
            }
            rcode[lr] = Bk;
            codes[row0 + lr] = Bk;
            codes_f[row0 + lr] = (float)Bk;
            atomicAdd(&counts[Bk], 1.0f);
        }
        __syncthreads();
    }
    __syncthreads();   // rcode complete

    // ---- fused music cosine via MFMA against the W panel (waves 0..3, mt=wave)
    if (wave < 4) {
        int mt = wave;
        f32x4 am = {0.f, 0.f, 0.f, 0.f};
        #pragma unroll
        for (int kb = 0; kb < 8; ++kb) {
            half8v av = *(const half8v*)&xh[(mt * 16 + lmod) * HSTR + lgrp * 8 + kb * 32];
            half8v wf = *(const half8v*)(wh + (((size_t)((kb << 2) + lgrp)) * 16 + lmod) * 8);
            am = __builtin_amdgcn_mfma_f32_16x16x32_f16(av, wf, am, 0, 0, 0);
        }
        float bias = (lmod < 3) ? bs[lmod] : 0.0f;
        #pragma unroll
        for (int i = 0; i < 4; ++i) {
            float m = am[i] + bias;
            float m1 = __shfl_down(m, 1, 64);
            float m2 = __shfl_down(m, 2, 64);
            if (lmod == 0) {
                int row = mt * 16 + lgrp * 4 + i;
                const float* mcp = mc + (size_t)b * (3 * T_) + (t0 + row);
                float c0 = mcp[0], c1v = mcp[T_], c2v = mcp[2 * T_];
                float num = m * c0 + m1 * c1v + m2 * c2v;
                float npn = fmaxf(sqrtf(m * m + m1 * m1 + m2 * m2), EPS_COS);
                float ncn = fmaxf(sqrtf(c0 * c0 + c1v * c1v + c2v * c2v), EPS_COS);
                sim[row0 + row] = num / (npn * ncn);
            }
        }
    }

    // ---- fused quantized output + commitment partial sum (all 8 waves)
    {
        const float* cbr = cb + (size_t)rcode[li] * D_;
        float* outb = out0 + (size_t)b * (D_ * T_) + t0 + li;
        const float* xbb = xb + t0 + li;
        float part = 0.0f;
        #pragma unroll 4
        for (int dd = 0; dd < 32; ++dd) {
            int d = dhi * 32 + dd;
            float qv = cbr[d];
            float xv = xbb[(size_t)d * T_];
            outb[(size_t)d * T_] = qv;
            float df = qv - xv;
            part = fmaf(df, df, part);
        }
        #pragma unroll
        for (int off = 32; off; off >>= 1) part += __shfl_down(part, off, 64);
        if (lane == 0) qpart[wave] = part;
        __syncthreads();
        if (tid == 0) {
            double s = (double)qpart[0] + qpart[1] + qpart[2] + qpart[3]
                     + qpart[4] + qpart[5] + qpart[6] + qpart[7];
            atomicAdd(&sums[0], s);
        }
    }
}

// ---------------------------------------------------------------------------
// Kernel 3: music loss sum
// ---------------------------------------------------------------------------
__global__ __launch_bounds__(256) void mloss_kernel(const float* __restrict__ sim,
                                                    const int* __restrict__ codes,
                                                    double* __restrict__ sums) {
    int idx = blockIdx.x * 256 + threadIdx.x;
    float val = 0.0f;
    if (idx < B_ * (T_ - 1)) {
        int b = idx / (T_ - 1);
        int t = idx - b * (T_ - 1);
        int base = b * T_ + t;
        if (codes[base + 1] != codes[base])
            val = fabsf(sim[base + 1] - sim[base]);
    }
    #pragma unroll
    for (int off = 32; off; off >>= 1) val += __shfl_down(val, off, 64);
    __shared__ float part[4];
    int lane = threadIdx.x & 63, wv = threadIdx.x >> 6;
    if (lane == 0) part[wv] = val;
    __syncthreads();
    if (threadIdx.x == 0) {
        double s = (double)part[0] + part[1] + part[2] + part[3];
        atomicAdd(&sums[1], s);
    }
}

// ---------------------------------------------------------------------------
// Kernel 4: finalize — perplexity + scalar outputs. Single block.
// ---------------------------------------------------------------------------
__global__ __launch_bounds__(256) void final_kernel(const float* __restrict__ counts,
                                                    const double* __restrict__ sums,
                                                    float* __restrict__ outS) {
    int tid = threadIdx.x;
    float e = 0.0f;
    for (int k = tid; k < K_; k += 256) {
        float p = counts[k] * (1.0f / (float)BT_);
        e += p * logf(p + 1e-10f);
    }
    #pragma unroll
    for (int off = 32; off; off >>= 1) e += __shfl_down(e, off, 64);
    __shared__ float part[4];
    int lane = tid & 63, wv = tid >> 6;
    if (lane == 0) part[wv] = e;
    __syncthreads();
    if (tid == 0) {
        float etot = part[0] + part[1] + part[2] + part[3];
        float perp = expf(-etot);
        float commitment = (float)(sums[0] / (double)BDT_);
        float ml = (float)(sums[1] / (double)(B_ * (T_ - 1)));
        outS[0] = commitment + MUSIC_W * ml;
        outS[1] = commitment;
        outS[2] = perp;
        outS[3] = ml;
    }
}

// ---------------------------------------------------------------------------
extern "C" void kernel_launch(void* const* d_in, const int* in_sizes, int n_in,
                              void* d_out, int out_size, void* d_ws, size_t ws_size,
                              hipStream_t stream) {
    const float* x   = (const float*)d_in[0];
    const float* mc  = (const float*)d_in[1];
    const float* cb  = (const float*)d_in[2];
    const float* wp  = (const float*)d_in[3];
    const float* bp  = (const float*)d_in[4];

    // workspace layout (float-offset units; sums first for 8B alignment)
    float* wsf = (float*)d_ws;
    double* sums     = (double*)wsf;               // 2 doubles  (4 floats)
    float* c2        = wsf + 4;                    // 1024
    float* sim       = c2 + K_;                    // 32768
    float* counts    = sim + BT_;                  // 1024
    int*   codes     = (int*)(counts + K_);        // 32768
    _Float16* cph    = (_Float16*)(codes + BT_);   // 262144 halfs
    _Float16* wh     = cph + (size_t)D_ * K_;      // 2048 halfs (W panel)

    float* out0    = (float*)d_out;                // quantized_st [16,256,2048]
    float* codes_f = out0 + BDT_;                  // codes [16,2048] as float
    float* outS    = codes_f + BT_;                // 4 scalars

    prep_kernel<<<K_, 256, 0, stream>>>(cb, wp, cph, wh, c2, counts, sums);
    argmin_kernel<<<BT_ / 64, 512, 0, stream>>>(x, mc, bp, cph, wh, cb, c2,
                                                codes, codes_f, sim, counts, out0, sums);
    mloss_kernel<<<(B_ * (T_ - 1) + 255) / 256, 256, 0, stream>>>(sim, codes, sums);
    final_kernel<<<1, 256, 0, stream>>>(counts, sums, outS);
}

// Round 15
// 92.066 us; speedup vs baseline: 1.3521x; 1.3521x over previous
//
#include <hip/hip_runtime.h>
#include <hip/hip_bf16.h>
#include <math.h>

// Problem constants
#define B_    16
#define D_    256
#define T_    2048
#define K_    1024
#define BT_   (B_ * T_)            // 32768 rows
#define BDT_  (B_ * D_ * T_)       // 8388608 elements
#define MUSIC_W 0.1f
#define EPS_COS 1e-8f
#define MARGIN_TAU 2e-4f           // > np ulp-grid (1.26e-4) + fp16 MFMA err + key quant (~4e-6)

typedef _Float16 half8v __attribute__((ext_vector_type(8)));
typedef float f32x4 __attribute__((ext_vector_type(4)));

// ---------------------------------------------------------------------------
// numpy pairwise sum-of-squares (exact replication for n=128 / n=256).
// ---------------------------------------------------------------------------
__device__ __forceinline__ float pw128_sq(const float* a, int stride) {
    float r[8];
    #pragma unroll
    for (int j = 0; j < 8; ++j) { float v = a[j * stride]; r[j] = __fmul_rn(v, v); }
    for (int i = 8; i < 128; i += 8) {
        #pragma unroll
        for (int j = 0; j < 8; ++j) {
            float v = a[(i + j) * stride];
            r[j] = __fadd_rn(r[j], __fmul_rn(v, v));
        }
    }
    return __fadd_rn(__fadd_rn(__fadd_rn(r[0], r[1]), __fadd_rn(r[2], r[3])),
                     __fadd_rn(__fadd_rn(r[4], r[5]), __fadd_rn(r[6], r[7])));
}
__device__ __forceinline__ float pw256_sq(const float* a, int stride) {
    return __fadd_rn(pw128_sq(a, stride), pw128_sq(a + 128 * stride, stride));
}

// np score for one (row, code): M = f32(round(f64 dot)); s = fl(fl(xx-2M)+cc).
__device__ __forceinline__ float np_score(const float* __restrict__ xr,
                                          const float* __restrict__ cp,
                                          float xxv, float c2k) {
    double a0 = 0.0, a1 = 0.0, a2 = 0.0, a3 = 0.0;
    for (int d = 0; d < 256; d += 4) {
        float4 cv = *(const float4*)(cp + d);
        a0 = fma((double)xr[d + 0], (double)cv.x, a0);
        a1 = fma((double)xr[d + 1], (double)cv.y, a1);
        a2 = fma((double)xr[d + 2], (double)cv.z, a2);
        a3 = fma((double)xr[d + 3], (double)cv.w, a3);
    }
    float M = (float)((a0 + a1) + (a2 + a3));
    return __fadd_rn(__fsub_rn(xxv, __fmul_rn(2.0f, M)), c2k);
}

// order-preserving key transforms (ascending)
__device__ __forceinline__ unsigned key_fwd(float s) {
    unsigned u = __float_as_uint(s);
    return u ^ ((unsigned)((int)u >> 31) | 0x80000000u);
}
__device__ __forceinline__ float key_inv(unsigned key) {
    unsigned u = (key & 0x80000000u) ? (key ^ 0x80000000u) : ~key;
    return __uint_as_float(u);
}

// ---------------------------------------------------------------------------
// Kernel 1: prep — cph packed fp16 codebook [d/8][k][8], wh fp16 W-panel,
// c2[k] numpy-pairwise, zero counts / sums.
// ---------------------------------------------------------------------------
__global__ __launch_bounds__(256) void prep_kernel(const float* __restrict__ cb,
                                                   const float* __restrict__ wp,
                                                   _Float16* __restrict__ cph,
                                                   _Float16* __restrict__ wh,
                                                   float* __restrict__ c2,
                                                   float* __restrict__ counts,
                                                   double* __restrict__ sums) {
    __shared__ float rr[16];
    int k = blockIdx.x;        // 0..1023
    int d = threadIdx.x;       // 0..255
    const float* a = cb + (size_t)k * D_;
    float v = a[d];
    cph[((d >> 3) * K_ + k) * 8 + (d & 7)] = (_Float16)v;
    if (k < 16) {
        _Float16 hv = (k < 3) ? (_Float16)wp[k * D_ + d] : (_Float16)0.0f;
        wh[((d >> 3) * 16 + k) * 8 + (d & 7)] = hv;
    }
    if (d < 8) {
        float acc = __fmul_rn(a[d], a[d]);
        for (int i = 8; i < 128; i += 8) acc = __fadd_rn(acc, __fmul_rn(a[i + d], a[i + d]));
        rr[d] = acc;
        float acc2 = __fmul_rn(a[128 + d], a[128 + d]);
        for (int i = 8; i < 128; i += 8) acc2 = __fadd_rn(acc2, __fmul_rn(a[128 + i + d], a[128 + i + d]));
        rr[8 + d] = acc2;
    }
    __syncthreads();
    if (d == 0) {
        float h1 = __fadd_rn(__fadd_rn(__fadd_rn(rr[0], rr[1]), __fadd_rn(rr[2], rr[3])),
                             __fadd_rn(__fadd_rn(rr[4], rr[5]), __fadd_rn(rr[6], rr[7])));
        float h2 = __fadd_rn(__fadd_rn(__fadd_rn(rr[8], rr[9]), __fadd_rn(rr[10], rr[11])),
                             __fadd_rn(__fadd_rn(rr[12], rr[13]), __fadd_rn(rr[14], rr[15])));
        c2[k] = __fadd_rn(h1, h2);
        counts[k] = 0.0f;
    }
    if (k == 0 && d < 2) sums[d] = 0.0;
}

// ---------------------------------------------------------------------------
// Kernel 2: mega-kernel — 64 rows/block, 256 threads, 512 blocks (R13 base).
// fp16 MFMA argmin with register double-buffered codebook fragments,
// packed-key top-2, candidate-only np fallback, fused music cosine,
// histogram, quantized output + commitment sum (x diff from LDS fp16 tile —
// no global x re-read; bias ~2e-8, negligible vs threshold).
// ---------------------------------------------------------------------------
#define HSTR 264   // fp16 tile row stride (halfs)

__global__ __launch_bounds__(256, 2) void argmin_kernel(const float* __restrict__ x,
                                                        const float* __restrict__ mc,
                                                        const float* __restrict__ bp,
                                                        const _Float16* __restrict__ cph,
                                                        const _Float16* __restrict__ wh,
                                                        const float* __restrict__ cb,
                                                        const float* __restrict__ c2,
                                                        int* __restrict__ codes,
                                                        float* __restrict__ codes_f,
                                                        float* __restrict__ sim,
                                                        float* __restrict__ counts,
                                                        float* __restrict__ out0,
                                                        double* __restrict__ sums) {
    __shared__ __align__(16) _Float16 xh[64 * HSTR];   // 33792 B
    __shared__ __align__(16) float xrow[256];
    __shared__ unsigned wb1[4][64], wb2[4][64];
    __shared__ float rbest[64];
    __shared__ int   rcode[64];
    __shared__ int   fb_list[64];
    __shared__ int   fb_n;
    __shared__ float fbv_s[4];
    __shared__ int   fbk_s[4];
    __shared__ float bs[3];
    __shared__ float qpart[4];

    int blk = blockIdx.x;            // 0..511
    int row0 = blk * 64;
    int b = row0 >> 11;
    int t0 = row0 & 2047;
    const float* xb = x + (size_t)b * (D_ * T_);

    int tid = threadIdx.x;
    if (tid == 0) fb_n = 0;
    if (tid < 3) bs[tid] = bp[tid];

    int wave = tid >> 6;
    int lane = tid & 63;
    int lmod = lane & 15;
    int lgrp = lane >> 4;            // 0..3

    // early prefetch: nt=0's B-fragments + c2 (global; independent of LDS)
    half8v bfrA[8], bfrB[8];
    {
        int n = wave * 256 + lmod;
        #pragma unroll
        for (int kb = 0; kb < 8; ++kb)
            bfrA[kb] = *(const half8v*)(cph + ((size_t)((kb << 2) + lgrp) * K_ + n) * 8);
    }
    float c2cur = c2[wave * 256 + lmod];

    // staging: thread (li, dhi) covers row t0+li, dims [dhi*64, dhi*64+64)
    int li = tid & 63;
    int dhi = tid >> 6;
    #pragma unroll
    for (int q = 0; q < 8; ++q) {
        half8v hv;
        #pragma unroll
        for (int j = 0; j < 8; ++j) {
            float v = xb[(size_t)(dhi * 64 + q * 8 + j) * T_ + t0 + li];
            hv[j] = (_Float16)v;
        }
        *(half8v*)&xh[li * HSTR + dhi * 64 + q * 8] = hv;
    }
    __syncthreads();

    // resident A fragments for m-tiles 0,1; mt 2,3 re-read from LDS per nt
    half8v afrag[2][8];
    #pragma unroll
    for (int mt = 0; mt < 2; ++mt)
        #pragma unroll
        for (int kb = 0; kb < 8; ++kb)
            afrag[mt][kb] = *(const half8v*)&xh[(mt * 16 + lmod) * HSTR + lgrp * 8 + kb * 32];

    // packed top-2 keys per row slot (16 slots: row = (r>>2)*16 + lgrp*4 + (r&3))
    unsigned b1[16], b2[16];
    #pragma unroll
    for (int r = 0; r < 16; ++r) { b1[r] = 0xFFFFFFFFu; b2[r] = 0xFFFFFFFFu; }

    // ---- main loop with register double-buffered B-fragments ----
    #pragma unroll 1
    for (int nt = 0; nt < 16; ++nt) {
        int n = wave * 256 + nt * 16 + lmod;
        // prefetch next tile's fragments + c2
        float c2nxt = 0.0f;
        if (nt < 15) {
            int n2 = n + 16;
            #pragma unroll
            for (int kb = 0; kb < 8; ++kb)
                bfrB[kb] = *(const half8v*)(cph + ((size_t)((kb << 2) + lgrp) * K_ + n2) * 8);
            c2nxt = c2[n2];
        }
        float c2n = c2cur;
        #pragma unroll
        for (int mt = 0; mt < 2; ++mt) {
            f32x4 acc = {0.f, 0.f, 0.f, 0.f};
            #pragma unroll
            for (int kb = 0; kb < 8; ++kb)
                acc = __builtin_amdgcn_mfma_f32_16x16x32_f16(afrag[mt][kb], bfrA[kb], acc, 0, 0, 0);
            #pragma unroll
            for (int i = 0; i < 4; ++i) {
                float s = fmaf(-2.0f, acc[i], c2n);
                unsigned u = (key_fwd(s) & 0xFFFFFC00u) | (unsigned)n;
                int r = mt * 4 + i;
                unsigned mx = b1[r] > u ? b1[r] : u;
                b1[r] = b1[r] < u ? b1[r] : u;
                b2[r] = b2[r] < mx ? b2[r] : mx;
            }
        }
        #pragma unroll
        for (int mt = 2; mt < 4; ++mt) {
            f32x4 acc = {0.f, 0.f, 0.f, 0.f};
            #pragma unroll
            for (int kb = 0; kb < 8; ++kb) {
                half8v av = *(const half8v*)&xh[(mt * 16 + lmod) * HSTR + lgrp * 8 + kb * 32];
                acc = __builtin_amdgcn_mfma_f32_16x16x32_f16(av, bfrA[kb], acc, 0, 0, 0);
            }
            #pragma unroll
            for (int i = 0; i < 4; ++i) {
                float s = fmaf(-2.0f, acc[i], c2n);
                unsigned u = (key_fwd(s) & 0xFFFFFC00u) | (unsigned)n;
                int r = mt * 4 + i;
                unsigned mx = b1[r] > u ? b1[r] : u;
                b1[r] = b1[r] < u ? b1[r] : u;
                b2[r] = b2[r] < mx ? b2[r] : mx;
            }
        }
        #pragma unroll
        for (int kb = 0; kb < 8; ++kb) bfrA[kb] = bfrB[kb];
        c2cur = c2nxt;
    }

    // cross-lane top-2 merge over the 16 lanes sharing lgrp
    #pragma unroll
    for (int r = 0; r < 16; ++r) {
        unsigned v1 = b1[r], v2 = b2[r];
        #pragma unroll
        for (int off = 1; off < 16; off <<= 1) {
            unsigned o1 = (unsigned)__shfl_xor((int)v1, off, 64);
            unsigned o2 = (unsigned)__shfl_xor((int)v2, off, 64);
            unsigned mx = v1 > o1 ? v1 : o1;
            v1 = v1 < o1 ? v1 : o1;
            unsigned m2 = v2 < o2 ? v2 : o2;
            v2 = m2 < mx ? m2 : mx;
        }
        if (lmod == 0) {
            int row = (r >> 2) * 16 + lgrp * 4 + (r & 3);
            wb1[wave][row] = v1; wb2[wave][row] = v2;
        }
    }
    __syncthreads();

    // cross-wave merge; commit wide-margin rows (+histogram), flag near-ties
    if (tid < 64) {
        unsigned B1 = wb1[0][tid], B2 = wb2[0][tid];
        #pragma unroll
        for (int w = 1; w < 4; ++w) {
            unsigned o1 = wb1[w][tid], o2 = wb2[w][tid];
            unsigned mx = B1 > o1 ? B1 : o1;
            B1 = B1 < o1 ? B1 : o1;
            unsigned m2 = B2 < o2 ? B2 : o2;
            B2 = m2 < mx ? m2 : mx;
        }
        float f1 = key_inv(B1 & 0xFFFFFC00u);
        float f2 = key_inv(B2 & 0xFFFFFC00u);
        rbest[tid] = f1;
        int row = row0 + tid;
        if (f2 - f1 >= MARGIN_TAU) {
            int bk = (int)(B1 & 1023u);
            rcode[tid] = bk;
            codes[row] = bk;
            codes_f[row] = (float)bk;
            atomicAdd(&counts[bk], 1.0f);
        } else {
            int slot = atomicAdd(&fb_n, 1);
            fb_list[slot] = tid;
        }
    }
    __syncthreads();

    // ---- candidate-only np-replication fallback for near-tie rows
    int nf = fb_n;
    for (int fi = 0; fi < nf; ++fi) {
        int lr = fb_list[fi];
        float rb = rbest[lr];
        xrow[tid] = xb[(size_t)tid * T_ + t0 + lr];   // exact f32 row (L2-warm)
        __syncthreads();

        int ri = (((lr >> 2) & 3) == lgrp) ? ((lr >> 4) * 4 + (lr & 3)) : -1;
        unsigned k1 = 0xFFFFFFFFu, k2 = 0xFFFFFFFFu;
        #pragma unroll
        for (int r = 0; r < 16; ++r) {
            if (r == ri) { k1 = b1[r]; k2 = b2[r]; }
        }
        float f1s = key_inv(k1 & 0xFFFFFC00u);
        float f2s = key_inv(k2 & 0xFFFFFC00u);
        int f1k = (int)(k1 & 1023u), f2k = (int)(k2 & 1023u);

        float xxv = pw256_sq(xrow, 1);   // np-pairwise |x|^2 (uniform LDS reads)

        float bv = 3.4e38f; int bk = -1;
        if (ri >= 0 && f1s <= rb + MARGIN_TAU) {
            bv = np_score(xrow, cb + (size_t)f1k * D_, xxv, c2[f1k]);
            bk = f1k;
        }
        if (ri >= 0 && f2s <= rb + MARGIN_TAU) {
            float sB = np_score(xrow, cb + (size_t)f2k * D_, xxv, c2[f2k]);
            if (sB < bv || (sB == bv && (unsigned)f2k < (unsigned)bk)) { bv = sB; bk = f2k; }
        }
        #pragma unroll
        for (int off = 1; off < 64; off <<= 1) {
            float ov = __shfl_xor(bv, off, 64);
            int ok = __shfl_xor(bk, off, 64);
            if (ov < bv || (ov == bv && (unsigned)ok < (unsigned)bk)) { bv = ov; bk = ok; }
        }
        if (lane == 0) { fbv_s[wave] = bv; fbk_s[wave] = bk; }
        __syncthreads();
        if (tid == 0) {
            float Bv = fbv_s[0]; int Bk = fbk_s[0];
            #pragma unroll
            for (int w = 1; w < 4; ++w) {
                if (fbv_s[w] < Bv || (fbv_s[w] == Bv && (unsigned)fbk_s[w] < (unsigned)Bk)) {
                    Bv = fbv_s[w]; Bk = fbk_s[w];
                }
            }
            rcode[lr] = Bk;
            codes[row0 + lr] = Bk;
            codes_f[row0 + lr] = (float)Bk;
            atomicAdd(&counts[Bk], 1.0f);
        }
        __syncthreads();
    }
    __syncthreads();   // rcode complete

    // ---- fused music cosine via MFMA against the W panel (mt = wave)
    {
        int mt = wave;
        f32x4 am = {0.f, 0.f, 0.f, 0.f};
        #pragma unroll
        for (int kb = 0; kb < 8; ++kb) {
            half8v av = *(const half8v*)&xh[(mt * 16 + lmod) * HSTR + lgrp * 8 + kb * 32];
            half8v wf = *(const half8v*)(wh + (((size_t)((kb << 2) + lgrp)) * 16 + lmod) * 8);
            am = __builtin_amdgcn_mfma_f32_16x16x32_f16(av, wf, am, 0, 0, 0);
        }
        float bias = (lmod < 3) ? bs[lmod] : 0.0f;
        #pragma unroll
        for (int i = 0; i < 4; ++i) {
            float m = am[i] + bias;
            float m1 = __shfl_down(m, 1, 64);
            float m2 = __shfl_down(m, 2, 64);
            if (lmod == 0) {
                int row = mt * 16 + lgrp * 4 + i;
                const float* mcp = mc + (size_t)b * (3 * T_) + (t0 + row);
                float c0 = mcp[0], c1v = mcp[T_], c2v = mcp[2 * T_];
                float num = m * c0 + m1 * c1v + m2 * c2v;
                float npn = fmaxf(sqrtf(m * m + m1 * m1 + m2 * m2), EPS_COS);
                float ncn = fmaxf(sqrtf(c0 * c0 + c1v * c1v + c2v * c2v), EPS_COS);
                sim[row0 + row] = num / (npn * ncn);
            }
        }
    }

    // ---- fused quantized output + commitment partial sum (x from LDS fp16)
    {
        const float* cbr = cb + (size_t)rcode[li] * D_;
        float* outb = out0 + (size_t)b * (D_ * T_) + t0 + li;
        float part = 0.0f;
        #pragma unroll 2
        for (int ch = 0; ch < 8; ++ch) {
            int d0 = dhi * 64 + ch * 8;
            half8v xv8 = *(const half8v*)&xh[li * HSTR + d0];
            float4 qa = *(const float4*)(cbr + d0);
            float4 qb = *(const float4*)(cbr + d0 + 4);
            float qs[8] = {qa.x, qa.y, qa.z, qa.w, qb.x, qb.y, qb.z, qb.w};
            #pragma unroll
            for (int j = 0; j < 8; ++j) {
                outb[(size_t)(d0 + j) * T_] = qs[j];
                float df = qs[j] - (float)xv8[j];
                part = fmaf(df, df, part);
            }
        }
        #pragma unroll
        for (int off = 32; off; off >>= 1) part += __shfl_down(part, off, 64);
        if (lane == 0) qpart[wave] = part;
        __syncthreads();
        if (tid == 0) {
            double s = (double)qpart[0] + qpart[1] + qpart[2] + qpart[3];
            atomicAdd(&sums[0], s);
        }
    }
}

// ---------------------------------------------------------------------------
// Kernel 3: music loss sum
// ---------------------------------------------------------------------------
__global__ __launch_bounds__(256) void mloss_kernel(const float* __restrict__ sim,
                                                    const int* __restrict__ codes,
                                                    double* __restrict__ sums) {
    int idx = blockIdx.x * 256 + threadIdx.x;
    float val = 0.0f;
    if (idx < B_ * (T_ - 1)) {
        int b = idx / (T_ - 1);
        int t = idx - b * (T_ - 1);
        int base = b * T_ + t;
        if (codes[base + 1] != codes[base])
            val = fabsf(sim[base + 1] - sim[base]);
    }
    #pragma unroll
    for (int off = 32; off; off >>= 1) val += __shfl_down(val, off, 64);
    __shared__ float part[4];
    int lane = threadIdx.x & 63, wv = threadIdx.x >> 6;
    if (lane == 0) part[wv] = val;
    __syncthreads();
    if (threadIdx.x == 0) {
        double s = (double)part[0] + part[1] + part[2] + part[3];
        atomicAdd(&sums[1], s);
    }
}

// ---------------------------------------------------------------------------
// Kernel 4: finalize — perplexity + scalar outputs. Single block.
// ---------------------------------------------------------------------------
__global__ __launch_bounds__(256) void final_kernel(const float* __restrict__ counts,
                                                    const double* __restrict__ sums,
                                                    float* __restrict__ outS) {
    int tid = threadIdx.x;
    float e = 0.0f;
    for (int k = tid; k < K_; k += 256) {
        float p = counts[k] * (1.0f / (float)BT_);
        e += p * logf(p + 1e-10f);
    }
    #pragma unroll
    for (int off = 32; off; off >>= 1) e += __shfl_down(e, off, 64);
    __shared__ float part[4];
    int lane = tid & 63, wv = tid >> 6;
    if (lane == 0) part[wv] = e;
    __syncthreads();
    if (tid == 0) {
        float etot = part[0] + part[1] + part[2] + part[3];
        float perp = expf(-etot);
        float commitment = (float)(sums[0] / (double)BDT_);
        float ml = (float)(sums[1] / (double)(B_ * (T_ - 1)));
        outS[0] = commitment + MUSIC_W * ml;
        outS[1] = commitment;
        outS[2] = perp;
        outS[3] = ml;
    }
}

// ---------------------------------------------------------------------------
extern "C" void kernel_launch(void* const* d_in, const int* in_sizes, int n_in,
                              void* d_out, int out_size, void* d_ws, size_t ws_size,
                              hipStream_t stream) {
    const float* x   = (const float*)d_in[0];
    const float* mc  = (const float*)d_in[1];
    const float* cb  = (const float*)d_in[2];
    const float* wp  = (const float*)d_in[3];
    const float* bp  = (const float*)d_in[4];

    // workspace layout (float-offset units; sums first for 8B alignment)
    float* wsf = (float*)d_ws;
    double* sums     = (double*)wsf;               // 2 doubles  (4 floats)
    float* c2        = wsf + 4;                    // 1024
    float* sim       = c2 + K_;                    // 32768
    float* counts    = sim + BT_;                  // 1024
    int*   codes     = (int*)(counts + K_);        // 32768
    _Float16* cph    = (_Float16*)(codes + BT_);   // 262144 halfs
    _Float16* wh     = cph + (size_t)D_ * K_;      // 2048 halfs (W panel)

    float* out0    = (float*)d_out;                // quantized_st [16,256,2048]
    float* codes_f = out0 + BDT_;                  // codes [16,2048] as float
    float* outS    = codes_f + BT_;                // 4 scalars

    prep_kernel<<<K_, 256, 0, stream>>>(cb, wp, cph, wh, c2, counts, sums);
    argmin_kernel<<<BT_ / 64, 256, 0, stream>>>(x, mc, bp, cph, wh, cb, c2,
                                                codes, codes_f, sim, counts, out0, sums);
    mloss_kernel<<<(B_ * (T_ - 1) + 255) / 256, 256, 0, stream>>>(sim, codes, sums);
    final_kernel<<<1, 256, 0, stream>>>(counts, sums, outS);
}

// Round 16
// 91.390 us; speedup vs baseline: 1.3621x; 1.0074x over previous
//
#include <hip/hip_runtime.h>
#include <hip/hip_bf16.h>
#include <math.h>

// Problem constants
#define B_    16
#define D_    256
#define T_    2048
#define K_    1024
#define BT_   (B_ * T_)            // 32768 rows
#define BDT_  (B_ * D_ * T_)       // 8388608 elements
#define MUSIC_W 0.1f
#define EPS_COS 1e-8f
#define MARGIN_TAU 2e-4f           // > np ulp-grid (1.26e-4) + fp16 MFMA err + key quant

typedef _Float16 half8v __attribute__((ext_vector_type(8)));
typedef float f32x4 __attribute__((ext_vector_type(4)));

// ---------------------------------------------------------------------------
// numpy pairwise sum-of-squares (exact replication for n=128 / n=256).
// ---------------------------------------------------------------------------
__device__ __forceinline__ float pw128_sq(const float* a, int stride) {
    float r[8];
    #pragma unroll
    for (int j = 0; j < 8; ++j) { float v = a[j * stride]; r[j] = __fmul_rn(v, v); }
    for (int i = 8; i < 128; i += 8) {
        #pragma unroll
        for (int j = 0; j < 8; ++j) {
            float v = a[(i + j) * stride];
            r[j] = __fadd_rn(r[j], __fmul_rn(v, v));
        }
    }
    return __fadd_rn(__fadd_rn(__fadd_rn(r[0], r[1]), __fadd_rn(r[2], r[3])),
                     __fadd_rn(__fadd_rn(r[4], r[5]), __fadd_rn(r[6], r[7])));
}
__device__ __forceinline__ float pw256_sq(const float* a, int stride) {
    return __fadd_rn(pw128_sq(a, stride), pw128_sq(a + 128 * stride, stride));
}

// np score for one (row, code): M = f32(round(f64 dot)); s = fl(fl(xx-2M)+cc).
__device__ __forceinline__ float np_score(const float* __restrict__ xr,
                                          const float* __restrict__ cp,
                                          float xxv, float c2k) {
    double a0 = 0.0, a1 = 0.0, a2 = 0.0, a3 = 0.0;
    for (int d = 0; d < 256; d += 4) {
        float4 cv = *(const float4*)(cp + d);
        a0 = fma((double)xr[d + 0], (double)cv.x, a0);
        a1 = fma((double)xr[d + 1], (double)cv.y, a1);
        a2 = fma((double)xr[d + 2], (double)cv.z, a2);
        a3 = fma((double)xr[d + 3], (double)cv.w, a3);
    }
    float M = (float)((a0 + a1) + (a2 + a3));
    return __fadd_rn(__fsub_rn(xxv, __fmul_rn(2.0f, M)), c2k);
}

// order-preserving key transforms (ascending)
__device__ __forceinline__ unsigned key_fwd(float s) {
    unsigned u = __float_as_uint(s);
    return u ^ ((unsigned)((int)u >> 31) | 0x80000000u);
}
__device__ __forceinline__ float key_inv(unsigned key) {
    unsigned u = (key & 0x80000000u) ? (key ^ 0x80000000u) : ~key;
    return __uint_as_float(u);
}

// ---------------------------------------------------------------------------
// Kernel 1: prep — 64 blocks x 16 codes. LDS-staged cb rows (coalesced reads),
// cph emitted as contiguous-k half8v runs (coalesced writes), c2 numpy-pairwise
// bit-exact, counts/sums/ticket zeroed, wh W-panel.
// ---------------------------------------------------------------------------
#define PREPK 16

__global__ __launch_bounds__(256) void prep_kernel(const float* __restrict__ cb,
                                                   const float* __restrict__ wp,
                                                   _Float16* __restrict__ cph,
                                                   _Float16* __restrict__ wh,
                                                   float* __restrict__ c2,
                                                   float* __restrict__ counts,
                                                   double* __restrict__ sums,
                                                   int* __restrict__ ticket) {
    __shared__ float cbl[PREPK * 256];   // 16 KB
    int k0 = blockIdx.x * PREPK;
    int tid = threadIdx.x;

    #pragma unroll
    for (int kk = 0; kk < PREPK; ++kk)
        cbl[kk * 256 + tid] = cb[(size_t)(k0 + kk) * D_ + tid];
    __syncthreads();

    // c2: np-pairwise, identical op order to reference replication
    if (tid < PREPK) {
        c2[k0 + tid] = pw256_sq(&cbl[tid * 256], 1);
        counts[k0 + tid] = 0.0f;
    }

    // cph [d/8][k][8]: pair p -> (octet o = p>>4, kk = p&15); 16 consecutive k
    // per octet give 256 B contiguous stores across 16 lanes.
    #pragma unroll
    for (int pp = 0; pp < 2; ++pp) {
        int p = tid + pp * 256;
        int o = p >> 4, kk = p & 15;
        half8v h;
        #pragma unroll
        for (int j = 0; j < 8; ++j) h[j] = (_Float16)cbl[kk * 256 + o * 8 + j];
        *(half8v*)&cph[((size_t)o * K_ + (k0 + kk)) * 8] = h;
    }

    if (blockIdx.x == 0) {
        int d = tid;
        #pragma unroll
        for (int kw = 0; kw < 16; ++kw) {
            _Float16 hv = (kw < 3) ? (_Float16)wp[kw * D_ + d] : (_Float16)0.0f;
            wh[((d >> 3) * 16 + kw) * 8 + (d & 7)] = hv;
        }
        if (tid < 2) sums[tid] = 0.0;
        if (tid == 2) *ticket = 0;
    }
}

// ---------------------------------------------------------------------------
// Kernel 2: mega-kernel — UNCHANGED from round 15 (82.5 µs proven).
// 64 rows/block, 256 threads, 512 blocks. fp16 MFMA argmin with register
// double-buffered codebook fragments, packed-key top-2, candidate-only np
// fallback, fused music cosine, histogram, quantized output + commitment sum.
// ---------------------------------------------------------------------------
#define HSTR 264   // fp16 tile row stride (halfs)

__global__ __launch_bounds__(256, 2) void argmin_kernel(const float* __restrict__ x,
                                                        const float* __restrict__ mc,
                                                        const float* __restrict__ bp,
                                                        const _Float16* __restrict__ cph,
                                                        const _Float16* __restrict__ wh,
                                                        const float* __restrict__ cb,
                                                        const float* __restrict__ c2,
                                                        int* __restrict__ codes,
                                                        float* __restrict__ codes_f,
                                                        float* __restrict__ sim,
                                                        float* __restrict__ counts,
                                                        float* __restrict__ out0,
                                                        double* __restrict__ sums) {
    __shared__ __align__(16) _Float16 xh[64 * HSTR];   // 33792 B
    __shared__ __align__(16) float xrow[256];
    __shared__ unsigned wb1[4][64], wb2[4][64];
    __shared__ float rbest[64];
    __shared__ int   rcode[64];
    __shared__ int   fb_list[64];
    __shared__ int   fb_n;
    __shared__ float fbv_s[4];
    __shared__ int   fbk_s[4];
    __shared__ float bs[3];
    __shared__ float qpart[4];

    int blk = blockIdx.x;            // 0..511
    int row0 = blk * 64;
    int b = row0 >> 11;
    int t0 = row0 & 2047;
    const float* xb = x + (size_t)b * (D_ * T_);

    int tid = threadIdx.x;
    if (tid == 0) fb_n = 0;
    if (tid < 3) bs[tid] = bp[tid];

    int wave = tid >> 6;
    int lane = tid & 63;
    int lmod = lane & 15;
    int lgrp = lane >> 4;            // 0..3

    // early prefetch: nt=0's B-fragments + c2 (global; independent of LDS)
    half8v bfrA[8], bfrB[8];
    {
        int n = wave * 256 + lmod;
        #pragma unroll
        for (int kb = 0; kb < 8; ++kb)
            bfrA[kb] = *(const half8v*)(cph + ((size_t)((kb << 2) + lgrp) * K_ + n) * 8);
    }
    float c2cur = c2[wave * 256 + lmod];

    // staging: thread (li, dhi) covers row t0+li, dims [dhi*64, dhi*64+64)
    int li = tid & 63;
    int dhi = tid >> 6;
    #pragma unroll
    for (int q = 0; q < 8; ++q) {
        half8v hv;
        #pragma unroll
        for (int j = 0; j < 8; ++j) {
            float v = xb[(size_t)(dhi * 64 + q * 8 + j) * T_ + t0 + li];
            hv[j] = (_Float16)v;
        }
        *(half8v*)&xh[li * HSTR + dhi * 64 + q * 8] = hv;
    }
    __syncthreads();

    // resident A fragments for m-tiles 0,1; mt 2,3 re-read from LDS per nt
    half8v afrag[2][8];
    #pragma unroll
    for (int mt = 0; mt < 2; ++mt)
        #pragma unroll
        for (int kb = 0; kb < 8; ++kb)
            afrag[mt][kb] = *(const half8v*)&xh[(mt * 16 + lmod) * HSTR + lgrp * 8 + kb * 32];

    // packed top-2 keys per row slot (16 slots: row = (r>>2)*16 + lgrp*4 + (r&3))
    unsigned b1[16], b2[16];
    #pragma unroll
    for (int r = 0; r < 16; ++r) { b1[r] = 0xFFFFFFFFu; b2[r] = 0xFFFFFFFFu; }

    // ---- main loop with register double-buffered B-fragments ----
    #pragma unroll 1
    for (int nt = 0; nt < 16; ++nt) {
        int n = wave * 256 + nt * 16 + lmod;
        float c2nxt = 0.0f;
        if (nt < 15) {
            int n2 = n + 16;
            #pragma unroll
            for (int kb = 0; kb < 8; ++kb)
                bfrB[kb] = *(const half8v*)(cph + ((size_t)((kb << 2) + lgrp) * K_ + n2) * 8);
            c2nxt = c2[n2];
        }
        float c2n = c2cur;
        #pragma unroll
        for (int mt = 0; mt < 2; ++mt) {
            f32x4 acc = {0.f, 0.f, 0.f, 0.f};
            #pragma unroll
            for (int kb = 0; kb < 8; ++kb)
                acc = __builtin_amdgcn_mfma_f32_16x16x32_f16(afrag[mt][kb], bfrA[kb], acc, 0, 0, 0);
            #pragma unroll
            for (int i = 0; i < 4; ++i) {
                float s = fmaf(-2.0f, acc[i], c2n);
                unsigned u = (key_fwd(s) & 0xFFFFFC00u) | (unsigned)n;
                int r = mt * 4 + i;
                unsigned mx = b1[r] > u ? b1[r] : u;
                b1[r] = b1[r] < u ? b1[r] : u;
                b2[r] = b2[r] < mx ? b2[r] : mx;
            }
        }
        #pragma unroll
        for (int mt = 2; mt < 4; ++mt) {
            f32x4 acc = {0.f, 0.f, 0.f, 0.f};
            #pragma unroll
            for (int kb = 0; kb < 8; ++kb) {
                half8v av = *(const half8v*)&xh[(mt * 16 + lmod) * HSTR + lgrp * 8 + kb * 32];
                acc = __builtin_amdgcn_mfma_f32_16x16x32_f16(av, bfrA[kb], acc, 0, 0, 0);
            }
            #pragma unroll
            for (int i = 0; i < 4; ++i) {
                float s = fmaf(-2.0f, acc[i], c2n);
                unsigned u = (key_fwd(s) & 0xFFFFFC00u) | (unsigned)n;
                int r = mt * 4 + i;
                unsigned mx = b1[r] > u ? b1[r] : u;
                b1[r] = b1[r] < u ? b1[r] : u;
                b2[r] = b2[r] < mx ? b2[r] : mx;
            }
        }
        #pragma unroll
        for (int kb = 0; kb < 8; ++kb) bfrA[kb] = bfrB[kb];
        c2cur = c2nxt;
    }

    // cross-lane top-2 merge over the 16 lanes sharing lgrp
    #pragma unroll
    for (int r = 0; r < 16; ++r) {
        unsigned v1 = b1[r], v2 = b2[r];
        #pragma unroll
        for (int off = 1; off < 16; off <<= 1) {
            unsigned o1 = (unsigned)__shfl_xor((int)v1, off, 64);
            unsigned o2 = (unsigned)__shfl_xor((int)v2, off, 64);
            unsigned mx = v1 > o1 ? v1 : o1;
            v1 = v1 < o1 ? v1 : o1;
            unsigned m2 = v2 < o2 ? v2 : o2;
            v2 = m2 < mx ? m2 : mx;
        }
        if (lmod == 0) {
            int row = (r >> 2) * 16 + lgrp * 4 + (r & 3);
            wb1[wave][row] = v1; wb2[wave][row] = v2;
        }
    }
    __syncthreads();

    // cross-wave merge; commit wide-margin rows (+histogram), flag near-ties
    if (tid < 64) {
        unsigned B1 = wb1[0][tid], B2 = wb2[0][tid];
        #pragma unroll
        for (int w = 1; w < 4; ++w) {
            unsigned o1 = wb1[w][tid], o2 = wb2[w][tid];
            unsigned mx = B1 > o1 ? B1 : o1;
            B1 = B1 < o1 ? B1 : o1;
            unsigned m2 = B2 < o2 ? B2 : o2;
            B2 = m2 < mx ? m2 : mx;
        }
        float f1 = key_inv(B1 & 0xFFFFFC00u);
        float f2 = key_inv(B2 & 0xFFFFFC00u);
        rbest[tid] = f1;
        int row = row0 + tid;
        if (f2 - f1 >= MARGIN_TAU) {
            int bk = (int)(B1 & 1023u);
            rcode[tid] = bk;
            codes[row] = bk;
            codes_f[row] = (float)bk;
            atomicAdd(&counts[bk], 1.0f);
        } else {
            int slot = atomicAdd(&fb_n, 1);
            fb_list[slot] = tid;
        }
    }
    __syncthreads();

    // ---- candidate-only np-replication fallback for near-tie rows
    int nf = fb_n;
    for (int fi = 0; fi < nf; ++fi) {
        int lr = fb_list[fi];
        float rb = rbest[lr];
        xrow[tid] = xb[(size_t)tid * T_ + t0 + lr];   // exact f32 row (L2-warm)
        __syncthreads();

        int ri = (((lr >> 2) & 3) == lgrp) ? ((lr >> 4) * 4 + (lr & 3)) : -1;
        unsigned k1 = 0xFFFFFFFFu, k2 = 0xFFFFFFFFu;
        #pragma unroll
        for (int r = 0; r < 16; ++r) {
            if (r == ri) { k1 = b1[r]; k2 = b2[r]; }
        }
        float f1s = key_inv(k1 & 0xFFFFFC00u);
        float f2s = key_inv(k2 & 0xFFFFFC00u);
        int f1k = (int)(k1 & 1023u), f2k = (int)(k2 & 1023u);

        float xxv = pw256_sq(xrow, 1);   // np-pairwise |x|^2 (uniform LDS reads)

        float bv = 3.4e38f; int bk = -1;
        if (ri >= 0 && f1s <= rb + MARGIN_TAU) {
            bv = np_score(xrow, cb + (size_t)f1k * D_, xxv, c2[f1k]);
            bk = f1k;
        }
        if (ri >= 0 && f2s <= rb + MARGIN_TAU) {
            float sB = np_score(xrow, cb + (size_t)f2k * D_, xxv, c2[f2k]);
            if (sB < bv || (sB == bv && (unsigned)f2k < (unsigned)bk)) { bv = sB; bk = f2k; }
        }
        #pragma unroll
        for (int off = 1; off < 64; off <<= 1) {
            float ov = __shfl_xor(bv, off, 64);
            int ok = __shfl_xor(bk, off, 64);
            if (ov < bv || (ov == bv && (unsigned)ok < (unsigned)bk)) { bv = ov; bk = ok; }
        }
        if (lane == 0) { fbv_s[wave] = bv; fbk_s[wave] = bk; }
        __syncthreads();
        if (tid == 0) {
            float Bv = fbv_s[0]; int Bk = fbk_s[0];
            #pragma unroll
            for (int w = 1; w < 4; ++w) {
                if (fbv_s[w] < Bv || (fbv_s[w] == Bv && (unsigned)fbk_s[w] < (unsigned)Bk)) {
                    Bv = fbv_s[w]; Bk = fbk_s[w];
                }
            }
            rcode[lr] = Bk;
            codes[row0 + lr] = Bk;
            codes_f[row0 + lr] = (float)Bk;
            atomicAdd(&counts[Bk], 1.0f);
        }
        __syncthreads();
    }
    __syncthreads();   // rcode complete

    // ---- fused music cosine via MFMA against the W panel (mt = wave)
    {
        int mt = wave;
        f32x4 am = {0.f, 0.f, 0.f, 0.f};
        #pragma unroll
        for (int kb = 0; kb < 8; ++kb) {
            half8v av = *(const half8v*)&xh[(mt * 16 + lmod) * HSTR + lgrp * 8 + kb * 32];
            half8v wf = *(const half8v*)(wh + (((size_t)((kb << 2) + lgrp)) * 16 + lmod) * 8);
            am = __builtin_amdgcn_mfma_f32_16x16x32_f16(av, wf, am, 0, 0, 0);
        }
        float bias = (lmod < 3) ? bs[lmod] : 0.0f;
        #pragma unroll
        for (int i = 0; i < 4; ++i) {
            float m = am[i] + bias;
            float m1 = __shfl_down(m, 1, 64);
            float m2 = __shfl_down(m, 2, 64);
            if (lmod == 0) {
                int row = mt * 16 + lgrp * 4 + i;
                const float* mcp = mc + (size_t)b * (3 * T_) + (t0 + row);
                float c0 = mcp[0], c1v = mcp[T_], c2v = mcp[2 * T_];
                float num = m * c0 + m1 * c1v + m2 * c2v;
                float npn = fmaxf(sqrtf(m * m + m1 * m1 + m2 * m2), EPS_COS);
                float ncn = fmaxf(sqrtf(c0 * c0 + c1v * c1v + c2v * c2v), EPS_COS);
                sim[row0 + row] = num / (npn * ncn);
            }
        }
    }

    // ---- fused quantized output + commitment partial sum (x from LDS fp16)
    {
        const float* cbr = cb + (size_t)rcode[li] * D_;
        float* outb = out0 + (size_t)b * (D_ * T_) + t0 + li;
        float part = 0.0f;
        #pragma unroll 2
        for (int ch = 0; ch < 8; ++ch) {
            int d0 = dhi * 64 + ch * 8;
            half8v xv8 = *(const half8v*)&xh[li * HSTR + d0];
            float4 qa = *(const float4*)(cbr + d0);
            float4 qb = *(const float4*)(cbr + d0 + 4);
            float qs[8] = {qa.x, qa.y, qa.z, qa.w, qb.x, qb.y, qb.z, qb.w};
            #pragma unroll
            for (int j = 0; j < 8; ++j) {
                outb[(size_t)(d0 + j) * T_] = qs[j];
                float df = qs[j] - (float)xv8[j];
                part = fmaf(df, df, part);
            }
        }
        #pragma unroll
        for (int off = 32; off; off >>= 1) part += __shfl_down(part, off, 64);
        if (lane == 0) qpart[wave] = part;
        __syncthreads();
        if (tid == 0) {
            double s = (double)qpart[0] + qpart[1] + qpart[2] + qpart[3];
            atomicAdd(&sums[0], s);
        }
    }
}

// ---------------------------------------------------------------------------
// Kernel 3: music loss sum + fused finalize (last-block ticket pattern).
// ---------------------------------------------------------------------------
__global__ __launch_bounds__(256) void mloss_final(const float* __restrict__ sim,
                                                   const int* __restrict__ codes,
                                                   const float* __restrict__ counts,
                                                   double* __restrict__ sums,
                                                   float* __restrict__ outS,
                                                   int* __restrict__ ticket) {
    __shared__ float part[4];
    __shared__ int is_last;
    int tid = threadIdx.x;
    int lane = tid & 63, wv = tid >> 6;

    int idx = blockIdx.x * 256 + tid;
    float val = 0.0f;
    if (idx < B_ * (T_ - 1)) {
        int b = idx / (T_ - 1);
        int t = idx - b * (T_ - 1);
        int base = b * T_ + t;
        if (codes[base + 1] != codes[base])
            val = fabsf(sim[base + 1] - sim[base]);
    }
    #pragma unroll
    for (int off = 32; off; off >>= 1) val += __shfl_down(val, off, 64);
    if (lane == 0) part[wv] = val;
    __syncthreads();
    if (tid == 0) {
        double s = (double)part[0] + part[1] + part[2] + part[3];
        atomicAdd(&sums[1], s);
        __threadfence();
        is_last = (atomicAdd(ticket, 1) == (int)gridDim.x - 1) ? 1 : 0;
    }
    __syncthreads();
    if (!is_last) return;

    // ---- finalize (last block only) ----
    float e = 0.0f;
    for (int k = tid; k < K_; k += 256) {
        float p = counts[k] * (1.0f / (float)BT_);
        e += p * logf(p + 1e-10f);
    }
    #pragma unroll
    for (int off = 32; off; off >>= 1) e += __shfl_down(e, off, 64);
    if (lane == 0) part[wv] = e;
    __syncthreads();
    if (tid == 0) {
        float etot = part[0] + part[1] + part[2] + part[3];
        float perp = expf(-etot);
        double s0 = atomicAdd(&sums[0], 0.0);
        double s1 = atomicAdd(&sums[1], 0.0);
        float commitment = (float)(s0 / (double)BDT_);
        float ml = (float)(s1 / (double)(B_ * (T_ - 1)));
        outS[0] = commitment + MUSIC_W * ml;
        outS[1] = commitment;
        outS[2] = perp;
        outS[3] = ml;
    }
}

// ---------------------------------------------------------------------------
extern "C" void kernel_launch(void* const* d_in, const int* in_sizes, int n_in,
                              void* d_out, int out_size, void* d_ws, size_t ws_size,
                              hipStream_t stream) {
    const float* x   = (const float*)d_in[0];
    const float* mc  = (const float*)d_in[1];
    const float* cb  = (const float*)d_in[2];
    const float* wp  = (const float*)d_in[3];
    const float* bp  = (const float*)d_in[4];

    // workspace layout (float-offset units; sums first for 8B alignment)
    float* wsf = (float*)d_ws;
    double* sums     = (double*)wsf;               // 2 doubles  (4 floats)
    float* c2        = wsf + 4;                    // 1024
    float* sim       = c2 + K_;                    // 32768
    float* counts    = sim + BT_;                  // 1024
    int*   codes     = (int*)(counts + K_);        // 32768
    _Float16* cph    = (_Float16*)(codes + BT_);   // 262144 halfs
    _Float16* wh     = cph + (size_t)D_ * K_;      // 2048 halfs (W panel)
    int*   ticket    = (int*)(wh + 2048);          // 1 int

    float* out0    = (float*)d_out;                // quantized_st [16,256,2048]
    float* codes_f = out0 + BDT_;                  // codes [16,2048] as float
    float* outS    = codes_f + BT_;                // 4 scalars

    prep_kernel<<<K_ / PREPK, 256, 0, stream>>>(cb, wp, cph, wh, c2, counts, sums, ticket);
    argmin_kernel<<<BT_ / 64, 256, 0, stream>>>(x, mc, bp, cph, wh, cb, c2,
                                                codes, codes_f, sim, counts, out0, sums);
    mloss_final<<<(B_ * (T_ - 1) + 255) / 256, 256, 0, stream>>>(sim, codes, counts,
                                                                 sums, outS, ticket);
}